// Round 10
// baseline (1965.357 us; speedup 1.0000x reference)
//
#include <hip/hip_runtime.h>
#include <hip/hip_fp16.h>

// Problem constants (HomogeneousGCN)
#define NND 200000
#define EED 6400000
#define GGD 1024
#define NBUCK 782   // ceil(N / 256) — CSR buckets of 256 nodes
#define CHUNK 8192  // edges per k_part block
#define SLOT  9000  // per-bucket slot capacity (mean 8184, sigma~90 -> 9 sigma)
// IN_C=128, HID=32, MLP_H=32, OUT=1, EPS=1e-5

// ---------------------------------------------------------------- CSR build, pass A:
// LDS counting sort within each 8192-edge chunk, then COALESCED write-out in
// LDS-index order (consecutive lanes -> consecutive global addresses).
__global__ __launch_bounds__(512) void k_part(const int* __restrict__ ei,
                                              int* __restrict__ bfill,
                                              int* __restrict__ pair, int e) {
    __shared__ int hist[NBUCK];
    __shared__ int loff[NBUCK + 1];
    __shared__ int adj[NBUCK];
    __shared__ int sorted[CHUNK];
    __shared__ int wsum[8], woff[8];
    int t = threadIdx.x;
    for (int i = t; i < NBUCK; i += 512) hist[i] = 0;
    __syncthreads();
    int e0 = blockIdx.x * CHUNK;
    int pr[16];                        // statically indexed, fits VGPRs
#pragma unroll
    for (int u = 0; u < 16; u++) {
        int i = e0 + t + u * 512;
        if (i < e) {
            int d = ei[e + i];
            int b = d >> 8;
            int r = atomicAdd(&hist[b], 1);
            pr[u] = (b << 21) | ((d & 255) << 13) | r;
        } else pr[u] = -1;
    }
    __syncthreads();
    // exclusive scan of hist[0..NBUCK) -> loff[0..NBUCK]
    int base2 = t * 2;
    int c0 = (base2 < NBUCK) ? hist[base2] : 0;
    int c1 = (base2 + 1 < NBUCK) ? hist[base2 + 1] : 0;
    int tot = c0 + c1;
    int lane = t & 63, w = t >> 6;     // 8 waves
    int v = tot;
    for (int d = 1; d < 64; d <<= 1) {
        int u2 = __shfl_up(v, d);
        if (lane >= d) v += u2;
    }
    if (lane == 63) wsum[w] = v;
    __syncthreads();
    if (t == 0) {
        int run = 0;
        for (int i = 0; i < 8; i++) { woff[i] = run; run += wsum[i]; }
    }
    __syncthreads();
    int off = woff[w] + (v - tot);
    if (base2 <= NBUCK) loff[base2] = off;
    if (base2 + 1 <= NBUCK) loff[base2 + 1] = off + c0;
    __syncthreads();
    // reserve global runs; adj[b] maps LDS index -> global index
    for (int i = t; i < NBUCK; i += 512) {
        int c = hist[i];
        int gb = (c > 0) ? atomicAdd(&bfill[i], c) : 0;
        adj[i] = i * SLOT + gb - loff[i];
    }
    __syncthreads();
    // scatter payload into LDS sorted order
#pragma unroll
    for (int u = 0; u < 16; u++) {
        int pv = pr[u];
        if (pv >= 0) {
            int i = e0 + t + u * 512;
            int s = ei[i];
            int b = pv >> 21;
            int dl = (pv >> 13) & 255;
            int r = pv & 8191;
            sorted[loff[b] + r] = (s << 8) | dl;
        }
    }
    __syncthreads();
    // coalesced write-out: binary-search bucket of each LDS index
    int nval = loff[NBUCK];
    for (int i = t; i < nval; i += 512) {
        int loB = 0, hiB = NBUCK;
        while (hiB - loB > 1) {
            int mid = (loB + hiB) >> 1;
            if (loff[mid] <= i) loB = mid; else hiB = mid;
        }
        int pos = i + adj[loB];
        if (pos - loB * SLOT < SLOT)        // overflow clamp (never in practice)
            pair[pos] = sorted[i];
    }
}

// ---------------------------------------------------------------- CSR build, pass B:
// one block per bucket: count 256 nodes in LDS, scan -> row_ptr/rcnt/dis, then
// scatter col within the bucket's L2-resident slot window.
__global__ __launch_bounds__(256) void k_fill2(const int* __restrict__ pair,
                                               const int* __restrict__ bfill,
                                               int* __restrict__ row_ptr,
                                               int* __restrict__ rcnt,
                                               float* __restrict__ dis,
                                               int* __restrict__ col,
                                               int nnodes) {
    __shared__ int lcnt[256];
    __shared__ int lrp[256];
    __shared__ int wsum[4];
    __shared__ int woff[4];
    int b = blockIdx.x;
    int t = threadIdx.x;
    int n0 = b << 8;
    int lo = b * SLOT;
    int cb = bfill[b];
    if (cb > SLOT) cb = SLOT;
    int hi = lo + cb;
    lcnt[t] = 0;
    __syncthreads();
    for (int i = lo + t; i < hi; i += 256)
        atomicAdd(&lcnt[pair[i] & 255], 1);
    __syncthreads();
    int c = lcnt[t];
    int lane = t & 63, w = t >> 6;
    int v = c;
    for (int d = 1; d < 64; d <<= 1) {
        int u = __shfl_up(v, d);
        if (lane >= d) v += u;
    }
    if (lane == 63) wsum[w] = v;
    __syncthreads();
    if (t == 0) {
        int run = 0;
        for (int i = 0; i < 4; i++) { woff[i] = run; run += wsum[i]; }
    }
    __syncthreads();
    int excl = woff[w] + (v - c);
    int node = n0 + t;
    lrp[t] = lo + excl;
    if (node < nnodes) {
        row_ptr[node] = lo + excl;
        rcnt[node] = c;
        dis[node] = rsqrtf((float)(c + 1));
    }
    lcnt[t] = 0;
    __syncthreads();
    for (int i = lo + t; i < hi; i += 256) {
        int p = pair[i];
        int dl = p & 255;
        int k = atomicAdd(&lcnt[dl], 1);
        col[lrp[dl] + k] = p >> 8;
    }
}

// ---------------------------------------------------------------- GEMM1: h' = (x @ W1) * dis[row]
__global__ __launch_bounds__(256) void k_gemm1(const float4* __restrict__ x4,
                                               const float* __restrict__ W,
                                               const float* __restrict__ dis,
                                               __half* __restrict__ h) {
    __shared__ float xs[64][132];
    __shared__ float wt[32][132];
    int t = threadIdx.x;
    int tile = blockIdx.x;
    for (int i = 0; i < 16; i++) {
        int idx = t + i * 256;
        int k = idx >> 5, j = idx & 31;
        wt[j][k] = W[idx];
    }
    const float4* xt = x4 + (size_t)tile * 2048;
    for (int i = 0; i < 8; i++) {
        int idx = t + i * 256;
        float4 f = xt[idx];
        int r = idx >> 5;
        int kc = (idx & 31) << 2;
        *(float4*)&xs[r][kc] = f;
    }
    __syncthreads();
    int j = t & 31, r = t >> 5;
    float acc[8];
#pragma unroll
    for (int i = 0; i < 8; i++) acc[i] = 0.f;
#pragma unroll
    for (int k4 = 0; k4 < 32; k4++) {
        float4 wv = *(const float4*)&wt[j][k4 * 4];
#pragma unroll
        for (int i = 0; i < 8; i++) {
            float4 xv = *(const float4*)&xs[r + i * 8][k4 * 4];
            acc[i] += xv.x * wv.x + xv.y * wv.y + xv.z * wv.z + xv.w * wv.w;
        }
    }
#pragma unroll
    for (int i = 0; i < 8; i++) {
        int n = tile * 64 + r + i * 8;
        h[(size_t)n * 32 + j] = __float2half(acc[i] * dis[n]);
    }
}

// ---------------------------------------------------------------- GEMM (layers 2,3):
__global__ __launch_bounds__(256) void k_gemm_s(const float4* __restrict__ c4,
                                                const float* __restrict__ W,
                                                const float* __restrict__ scale,
                                                const float* __restrict__ shift,
                                                const float* __restrict__ dis,
                                                __half* __restrict__ h, int nnodes) {
    __shared__ float cs[128][36];
    __shared__ float wt[32][36];
    int t = threadIdx.x;
    for (int i = 0; i < 4; i++) {
        int idx = t + i * 256;
        int k = idx >> 5, j = idx & 31;
        wt[j][k] = W[idx];
    }
    int nbase = blockIdx.x * 128;
    int j0 = (t & 7) * 4;
    float4 sc = *(const float4*)&scale[j0];
    float4 sh = *(const float4*)&shift[j0];
    for (int i = 0; i < 4; i++) {
        int idx = t + i * 256;
        int r = idx >> 3;
        int kc = (idx & 7) * 4;
        int n = nbase + r;
        float4 f;
        if (n < nnodes) f = c4[(size_t)nbase * 8 + idx];
        else f = make_float4(0.f, 0.f, 0.f, 0.f);
        f.x = fmaxf(f.x * sc.x + sh.x, 0.f);
        f.y = fmaxf(f.y * sc.y + sh.y, 0.f);
        f.z = fmaxf(f.z * sc.z + sh.z, 0.f);
        f.w = fmaxf(f.w * sc.w + sh.w, 0.f);
        *(float4*)&cs[r][kc] = f;
    }
    __syncthreads();
    int j = t & 31, r = t >> 5;
    float acc[16];
#pragma unroll
    for (int i = 0; i < 16; i++) acc[i] = 0.f;
#pragma unroll
    for (int k4 = 0; k4 < 8; k4++) {
        float4 wv = *(const float4*)&wt[j][k4 * 4];
#pragma unroll
        for (int i = 0; i < 16; i++) {
            float4 xv = *(const float4*)&cs[r + i * 8][k4 * 4];
            acc[i] += xv.x * wv.x + xv.y * wv.y + xv.z * wv.z + xv.w * wv.w;
        }
    }
#pragma unroll
    for (int i = 0; i < 16; i++) {
        int n = nbase + r + i * 8;
        if (n < nnodes) h[(size_t)n * 32 + j] = __float2half(acc[i] * dis[n]);
    }
}

// ---------------------------------------------------------------- aggregation v2:
// ONE WAVE PER NODE. Per iteration: 8 edges x 8 lanes x uint2(8B) = 8 full 64B
// lines from one load instruction; x2 manual unroll = 16 lines in flight.
// Cross-group shfl_xor reduce; lanes 0-7 add self term, write float4.
// BN sum/sumsq fused (do_stats): removes the separate N-wide k_stats pass.
// Replaces r9 k_agg: per-lane 2B loads, latency-serial iters, 2.69TB/s.
__global__ __launch_bounds__(256) void k_agg(const __half* __restrict__ h,
                                             const int* __restrict__ row_ptr,
                                             const int* __restrict__ rcnt,
                                             const int* __restrict__ col,
                                             const float* __restrict__ dis,
                                             const float* __restrict__ bias,
                                             float* __restrict__ c,
                                             float* __restrict__ gsum,
                                             float* __restrict__ gsq,
                                             int nnodes, int do_stats) {
    __shared__ float ls[32], lq[32];
    int t = threadIdx.x;
    if (do_stats) {
        if (t < 32) { ls[t] = 0.f; lq[t] = 0.f; }
        __syncthreads();
    }
    int wv = t >> 6;          // wave 0..3 -> node
    int lane = t & 63;
    int g = lane >> 3;        // edge group 0..7
    int jq = lane & 7;        // column quad 0..7 (4 cols each)
    int n = blockIdx.x * 4 + wv;
    float4 acc = make_float4(0.f, 0.f, 0.f, 0.f);
    int e0 = 0, deg = 0, e1 = 0;
    if (n < nnodes) {
        e0 = row_ptr[n];
        deg = rcnt[n];
        e1 = e0 + deg;
    }
    if (deg > 0) {
        int nit = (deg + 7) >> 3;
        int ee = e0 + g;
        for (int it = 0; it < nit; it += 2) {
            // iter A (mask-predicated tail, clamped index stays in bucket)
            int iA = ee < e1 ? ee : e1 - 1;
            float mA = ee < e1 ? 1.f : 0.f;
            int sA = col[iA];
            uint2 hA = *(const uint2*)(h + (size_t)sA * 32 + jq * 4);
            // iter B
            int eB = ee + 8;
            int iB = eB < e1 ? eB : e1 - 1;
            float mB = (it + 1 < nit && eB < e1) ? 1.f : 0.f;
            int sB = col[iB];
            uint2 hB = *(const uint2*)(h + (size_t)sB * 32 + jq * 4);
            float2 a0 = __half22float2(*(__half2*)&hA.x);
            float2 a1 = __half22float2(*(__half2*)&hA.y);
            float2 b0 = __half22float2(*(__half2*)&hB.x);
            float2 b1 = __half22float2(*(__half2*)&hB.y);
            acc.x = fmaf(mA, a0.x, fmaf(mB, b0.x, acc.x));
            acc.y = fmaf(mA, a0.y, fmaf(mB, b0.y, acc.y));
            acc.z = fmaf(mA, a1.x, fmaf(mB, b1.x, acc.z));
            acc.w = fmaf(mA, a1.y, fmaf(mB, b1.y, acc.w));
            ee += 16;
        }
    }
    // reduce across the 8 edge groups
#pragma unroll
    for (int d = 8; d < 64; d <<= 1) {
        acc.x += __shfl_xor(acc.x, d);
        acc.y += __shfl_xor(acc.y, d);
        acc.z += __shfl_xor(acc.z, d);
        acc.w += __shfl_xor(acc.w, d);
    }
    if (n < nnodes && g == 0) {
        uint2 sv = *(const uint2*)(h + (size_t)n * 32 + jq * 4);
        float2 s0 = __half22float2(*(__half2*)&sv.x);
        float2 s1 = __half22float2(*(__half2*)&sv.y);
        float dn = dis[n];
        float4 bj = *(const float4*)&bias[jq * 4];
        float4 vv;
        vv.x = (acc.x + s0.x) * dn + bj.x;
        vv.y = (acc.y + s0.y) * dn + bj.y;
        vv.z = (acc.z + s1.x) * dn + bj.z;
        vv.w = (acc.w + s1.y) * dn + bj.w;
        *(float4*)&c[(size_t)n * 32 + jq * 4] = vv;
        if (do_stats) {
            int jb = jq * 4;
            atomicAdd(&ls[jb + 0], vv.x); atomicAdd(&lq[jb + 0], vv.x * vv.x);
            atomicAdd(&ls[jb + 1], vv.y); atomicAdd(&lq[jb + 1], vv.y * vv.y);
            atomicAdd(&ls[jb + 2], vv.z); atomicAdd(&lq[jb + 2], vv.z * vv.z);
            atomicAdd(&ls[jb + 3], vv.w); atomicAdd(&lq[jb + 3], vv.w * vv.w);
        }
    }
    if (do_stats) {
        __syncthreads();
        if (t < 32) { atomicAdd(&gsum[t], ls[t]); atomicAdd(&gsq[t], lq[t]); }
    }
}

// ---------------------------------------------------------------- BN stats (MLP head only)
__global__ __launch_bounds__(256) void k_stats(const float* __restrict__ c,
                                               float* __restrict__ gsum,
                                               float* __restrict__ gsq, int total) {
    __shared__ float ls[32], lq[32];
    int t = threadIdx.x;
    if (t < 32) { ls[t] = 0.f; lq[t] = 0.f; }
    __syncthreads();
    int j = t & 31;
    float s = 0.f, q = 0.f;
    int stride = gridDim.x * 256;
    for (int i = blockIdx.x * 256 + t; i < total; i += stride) {
        float v = c[i];
        s += v;
        q += v * v;
    }
    atomicAdd(&ls[j], s);
    atomicAdd(&lq[j], q);
    __syncthreads();
    if (t < 32) {
        atomicAdd(&gsum[t], ls[t]);
        atomicAdd(&gsq[t], lq[t]);
    }
}

__global__ void k_finalize(float* __restrict__ gsum, float* __restrict__ gsq,
                           const float* __restrict__ g, const float* __restrict__ be,
                           float* __restrict__ scale, float* __restrict__ shift,
                           float invN) {
    int t = threadIdx.x;
    if (t < 32) {
        float m = gsum[t] * invN;
        float v = gsq[t] * invN - m * m;
        float sc = g[t] * rsqrtf(v + 1e-5f);
        scale[t] = sc;
        shift[t] = be[t] - m * sc;
        gsum[t] = 0.f;   // reset for next stats pass
        gsq[t] = 0.f;
    }
}

// ---------------------------------------------------------------- pooling (batch sorted)
__global__ __launch_bounds__(256) void k_pool(const float* __restrict__ c,
                                              const int* __restrict__ batch,
                                              float* __restrict__ pooled, int nnodes) {
    int t = threadIdx.x;
    int j = t & 31, grp = t >> 5;
    int n0 = blockIdx.x * 1024 + grp * 128;
    if (n0 >= nnodes) return;
    int n1 = n0 + 128;
    if (n1 > nnodes) n1 = nnodes;
    int cur = batch[n0];
    float acc = 0.f;
    for (int n = n0; n < n1; n++) {
        int b = batch[n];
        if (b != cur) {
            atomicAdd(&pooled[(size_t)cur * 32 + j], acc);
            cur = b;
            acc = 0.f;
        }
        acc += c[(size_t)n * 32 + j];
    }
    atomicAdd(&pooled[(size_t)cur * 32 + j], acc);
}

// ---------------------------------------------------------------- MLP linear
__global__ __launch_bounds__(256) void m_lin(const float4* __restrict__ x4,
                                             const float* __restrict__ W,
                                             const float* __restrict__ bias,
                                             const float* __restrict__ scale,
                                             const float* __restrict__ shift,
                                             float* __restrict__ y,
                                             int use_bn) {
    __shared__ float cs[128][36];
    __shared__ float wt[32][36];
    int t = threadIdx.x;
    for (int i = 0; i < 4; i++) {
        int idx = t + i * 256;
        int k = idx >> 5, j = idx & 31;
        wt[j][k] = W[idx];
    }
    int nbase = blockIdx.x * 128;
    int j0 = (t & 7) * 4;
    float4 sc = make_float4(1.f, 1.f, 1.f, 1.f);
    float4 sh = make_float4(0.f, 0.f, 0.f, 0.f);
    if (use_bn) { sc = *(const float4*)&scale[j0]; sh = *(const float4*)&shift[j0]; }
    for (int i = 0; i < 4; i++) {
        int idx = t + i * 256;
        int r = idx >> 3;
        int kc = (idx & 7) * 4;
        float4 f = x4[(size_t)nbase * 8 + idx];
        if (use_bn) {
            f.x = fmaxf(f.x * sc.x + sh.x, 0.f);
            f.y = fmaxf(f.y * sc.y + sh.y, 0.f);
            f.z = fmaxf(f.z * sc.z + sh.z, 0.f);
            f.w = fmaxf(f.w * sc.w + sh.w, 0.f);
        }
        *(float4*)&cs[r][kc] = f;
    }
    __syncthreads();
    int j = t & 31, r = t >> 5;
    float bj = bias[j];
    float acc[16];
#pragma unroll
    for (int i = 0; i < 16; i++) acc[i] = 0.f;
#pragma unroll
    for (int k4 = 0; k4 < 8; k4++) {
        float4 wv = *(const float4*)&wt[j][k4 * 4];
#pragma unroll
        for (int i = 0; i < 16; i++) {
            float4 xv = *(const float4*)&cs[r + i * 8][k4 * 4];
            acc[i] += xv.x * wv.x + xv.y * wv.y + xv.z * wv.z + xv.w * wv.w;
        }
    }
#pragma unroll
    for (int i = 0; i < 16; i++) {
        int n = nbase + r + i * 8;
        y[(size_t)n * 32 + j] = acc[i] + bj;
    }
}

// ---------------------------------------------------------------- MLP out: 32 -> 1
__global__ __launch_bounds__(256) void m_out(const float* __restrict__ h,
        const float* __restrict__ scale, const float* __restrict__ shift,
        const float* __restrict__ M3, const float* __restrict__ mb3,
        float* __restrict__ out) {
    __shared__ float w3[32], sc_s[32], sh_s[32];
    int t = threadIdx.x;
    if (t < 32) { w3[t] = M3[t]; sc_s[t] = scale[t]; sh_s[t] = shift[t]; }
    __syncthreads();
    int r = blockIdx.x * 256 + t;
    const float4* row = (const float4*)(h + (size_t)r * 32);
    float o = mb3[0];
#pragma unroll
    for (int k4 = 0; k4 < 8; k4++) {
        float4 f = row[k4];
        int k = k4 * 4;
        o += fmaxf(f.x * sc_s[k + 0] + sh_s[k + 0], 0.f) * w3[k + 0];
        o += fmaxf(f.y * sc_s[k + 1] + sh_s[k + 1], 0.f) * w3[k + 1];
        o += fmaxf(f.z * sc_s[k + 2] + sh_s[k + 2], 0.f) * w3[k + 2];
        o += fmaxf(f.w * sc_s[k + 3] + sh_s[k + 3], 0.f) * w3[k + 3];
    }
    out[r] = o;
}

// ----------------------------------------------------------------
extern "C" void kernel_launch(void* const* d_in, const int* in_sizes, int n_in,
                              void* d_out, int out_size, void* d_ws, size_t ws_size,
                              hipStream_t stream) {
    const int N = NND, E = EED;
    const float* x  = (const float*)d_in[0];
    const int* ei   = (const int*)d_in[1];    // [2][E]: src = ei[0..E), dst = ei[E..2E)
    const int* batch= (const int*)d_in[2];
    const float* W1 = (const float*)d_in[3];
    const float* b1 = (const float*)d_in[4];
    const float* g1 = (const float*)d_in[5];
    const float* be1= (const float*)d_in[6];
    const float* W2 = (const float*)d_in[7];
    const float* b2 = (const float*)d_in[8];
    const float* g2 = (const float*)d_in[9];
    const float* be2= (const float*)d_in[10];
    const float* W3 = (const float*)d_in[11];
    const float* b3 = (const float*)d_in[12];
    const float* M1 = (const float*)d_in[13];
    const float* mb1= (const float*)d_in[14];
    const float* mg1= (const float*)d_in[15];
    const float* mbe1=(const float*)d_in[16];
    const float* M2 = (const float*)d_in[17];
    const float* mb2= (const float*)d_in[18];
    const float* mg2= (const float*)d_in[19];
    const float* mbe2=(const float*)d_in[20];
    const float* M3 = (const float*)d_in[21];
    const float* mb3= (const float*)d_in[22];
    float* out = (float*)d_out;

    // workspace carve-up (256B aligned); zeroed arrays first
    char* wp = (char*)d_ws;
    auto alloc = [&](size_t bytes) -> void* {
        void* p = (void*)wp;
        wp += (bytes + 255) & ~(size_t)255;
        return p;
    };
    int* bfill    = (int*)alloc((size_t)NBUCK * 4);
    float* gsum   = (float*)alloc(32 * 4);
    float* gsq    = (float*)alloc(32 * 4);
    float* pooled = (float*)alloc((size_t)GGD * 32 * 4);
    size_t zero_bytes = (size_t)(wp - (char*)d_ws);
    int* row_ptr  = (int*)alloc((size_t)N * 4);
    int* rcnt     = (int*)alloc((size_t)N * 4);
    float* dis    = (float*)alloc((size_t)N * 4);
    int* col      = (int*)alloc((size_t)NBUCK * SLOT * 4);
    // pair buffer (28.2MB) aliased onto hbuf(fp16)+cbuf (dead after CSR build)
    char* big     = (char*)alloc((size_t)E * 8 + 512);
    __half* hbuf  = (__half*)big;
    float* cbuf   = (float*)(big + (((size_t)N * 32 * 4 + 255) & ~(size_t)255));
    int* pair     = (int*)big;
    float* scale  = (float*)alloc(32 * 4);
    float* shift  = (float*)alloc(32 * 4);
    float* y1     = (float*)alloc((size_t)GGD * 32 * 4);
    float* y2     = (float*)alloc((size_t)GGD * 32 * 4);

    hipMemsetAsync(d_ws, 0, zero_bytes, stream);

    // CSR build: LDS-sorted slotted partition -> per-bucket fill
    const int nbE = (E + CHUNK - 1) / CHUNK;   // 782
    k_part<<<nbE, 512, 0, stream>>>(ei, bfill, pair, E);
    k_fill2<<<NBUCK, 256, 0, stream>>>(pair, bfill, row_ptr, rcnt, dis, col, N);

    const float invN = 1.f / (float)N;
    const int aggGrid = (N + 3) / 4;
    // ---- layer 1 (stats fused into k_agg)
    k_gemm1<<<N / 64, 256, 0, stream>>>((const float4*)x, W1, dis, hbuf);
    k_agg<<<aggGrid, 256, 0, stream>>>(hbuf, row_ptr, rcnt, col, dis, b1, cbuf, gsum, gsq, N, 1);
    k_finalize<<<1, 64, 0, stream>>>(gsum, gsq, g1, be1, scale, shift, invN);
    // ---- layer 2
    k_gemm_s<<<(N + 127) / 128, 256, 0, stream>>>((const float4*)cbuf, W2, scale, shift, dis, hbuf, N);
    k_agg<<<aggGrid, 256, 0, stream>>>(hbuf, row_ptr, rcnt, col, dis, b2, cbuf, gsum, gsq, N, 1);
    k_finalize<<<1, 64, 0, stream>>>(gsum, gsq, g2, be2, scale, shift, invN);
    // ---- layer 3 (no stats)
    k_gemm_s<<<(N + 127) / 128, 256, 0, stream>>>((const float4*)cbuf, W3, scale, shift, dis, hbuf, N);
    k_agg<<<aggGrid, 256, 0, stream>>>(hbuf, row_ptr, rcnt, col, dis, b3, cbuf, gsum, gsq, N, 0);
    // ---- pool
    k_pool<<<(N + 1023) / 1024, 256, 0, stream>>>(cbuf, batch, pooled, N);
    // ---- MLP head
    const float invG = 1.f / (float)GGD;
    m_lin<<<GGD / 128, 256, 0, stream>>>((const float4*)pooled, M1, mb1, nullptr, nullptr, y1, 0);
    k_stats<<<64, 256, 0, stream>>>(y1, gsum, gsq, GGD * 32);
    k_finalize<<<1, 64, 0, stream>>>(gsum, gsq, mg1, mbe1, scale, shift, invG);
    m_lin<<<GGD / 128, 256, 0, stream>>>((const float4*)y1, M2, mb2, scale, shift, y2, 1);
    k_stats<<<64, 256, 0, stream>>>(y2, gsum, gsq, GGD * 32);
    k_finalize<<<1, 64, 0, stream>>>(gsum, gsq, mg2, mbe2, scale, shift, invG);
    m_out<<<GGD / 256, 256, 0, stream>>>(y2, scale, shift, M3, mb3, out);
}